// Round 7
// baseline (638.953 us; speedup 1.0000x reference)
//
#include <hip/hip_runtime.h>
#include <hip/hip_cooperative_groups.h>

// GIN: 3 layers of {agg = scatter_sum(h[src] -> dst); h = relu(((1+eps)h + agg) @ W + b)}
// then per-graph segment-sum readout (graph_ids sorted) -> 2-layer MLP.
//
// R20: layers are at their memory-path floor (R19: occupancy 42->66% yet BW
//      DROPPED 2.74->2.28 TB/s -> random-gather path saturated; ILP closed
//      by R14-R18). Layer reverted to R18 verbatim (50.5us). Attack moves to
//      the ~155us non-layer chain:
//      (a) prep chain (pre+colscan+bucket_base+scatter+csr_build) fused into
//          ONE cooperative kernel, grid.sync between phases; bucket_base
//          eliminated (bbase recomputed locally from btot via LDS scan;
//          offsets[N]=E produced by bucket 195's csr phase write);
//      (b) readout_part vectorized: uint2 loads, 4 nodes/wave-iter,
//          shfl_xor cross-node reduce (was 2B/lane scalar over 38.4MB).
// R18: flat-batch gather (best layer: 50.5us). R13: uniform-trip gather.
// R12: merged pre. R10: fused layer + atomic-free readout. R9: bucketed CSR.
// R7: f16 H. R5: MFMA bf16 hi/lo 3-product gemm.

namespace cg = cooperative_groups;

#define SPLIT 16
#define NBLK 512     // prep grid size / edge chunks
#define BS 512       // nodes per bucket (pow2)

typedef unsigned short ushort_t;
typedef __bf16 v8bf __attribute__((ext_vector_type(8)));
typedef float v4f __attribute__((ext_vector_type(4)));

__device__ __forceinline__ float h2f_lo(unsigned int v) {
    return (float)__builtin_bit_cast(_Float16, (unsigned short)(v & 0xffffu));
}
__device__ __forceinline__ float h2f_hi(unsigned int v) {
    return (float)__builtin_bit_cast(_Float16, (unsigned short)(v >> 16));
}
__device__ __forceinline__ unsigned int f2h(float f) {
    return (unsigned int)__builtin_bit_cast(unsigned short, (_Float16)f);
}

// ---- R20 fused prep (cooperative): count | cast | Wprep || colscan ||
//      scatter || csr_build.  All blocks execute every grid.sync.
__global__ __launch_bounds__(256) void prep_coop_kernel(
        const int* __restrict__ src, const int* __restrict__ dst,
        const float* __restrict__ x, const float* __restrict__ W,
        int* __restrict__ cnt2d, int* __restrict__ btot,
        int* __restrict__ blkoff, unsigned int* __restrict__ bkt,
        int* __restrict__ csr, int* __restrict__ offsets,
        ushort_t* __restrict__ xh, ushort_t* __restrict__ whi,
        ushort_t* __restrict__ wlo,
        int N, int E, int nbkt, int ebpb, int n4, int wtotal) {
    cg::grid_group grid = cg::this_grid();
    __shared__ int shA[BS];       // cnt / lbase
    __shared__ int shB[BS];       // rank / lrank / exclusive-bbase
    __shared__ int shS[256];      // scans
    int t = threadIdx.x;
    int blk = blockIdx.x;

    // ---- P0: per-chunk bucket histogram + x cast + W split ----
    shA[t] = 0;
    __syncthreads();
    {
        int base = blk * ebpb;
        int end = min(base + ebpb, E);
        for (int i = base + t; i < end; i += 256)
            atomicAdd(&shA[dst[i] >> 9], 1);
    }
    __syncthreads();
    if (t < nbkt) cnt2d[(size_t)blk * nbkt + t] = shA[t];
    for (int i = blk * 256 + t; i < n4; i += NBLK * 256) {
        float4 v = ((const float4*)x)[i];
        uint2 p;
        p.x = f2h(v.x) | (f2h(v.y) << 16);
        p.y = f2h(v.z) | (f2h(v.w) << 16);
        ((uint2*)xh)[i] = p;
    }
    for (int i = blk * 256 + t; i < wtotal; i += NBLK * 256) {
        int l = i >> 12, r = i & 4095;
        int n = r >> 6, k = r & 63;
        float w = W[l * 4096 + k * 64 + n];
        __bf16 h = (__bf16)w;
        float rem = w - (float)h;
        whi[i] = __builtin_bit_cast(ushort_t, h);
        wlo[i] = __builtin_bit_cast(ushort_t, (__bf16)rem);
    }
    __threadfence();
    grid.sync();

    // ---- P1: colscan (blocks 0..nbkt-1): column b of cnt2d -> blkoff, btot
    if (blk < nbkt) {
        int b = blk;
        int i0 = 2 * t, i1 = 2 * t + 1;
        int v0 = cnt2d[(size_t)i0 * nbkt + b];
        int v1 = cnt2d[(size_t)i1 * nbkt + b];
        int pair = v0 + v1;
        shS[t] = pair;
        __syncthreads();
        for (int off = 1; off < 256; off <<= 1) {
            int u = (t >= off) ? shS[t - off] : 0;
            __syncthreads();
            shS[t] += u;
            __syncthreads();
        }
        int ex = shS[t] - pair;
        blkoff[(size_t)b * NBLK + i0] = ex;
        blkoff[(size_t)b * NBLK + i1] = ex + v0;
        if (t == 255) btot[b] = shS[255];
    }
    __threadfence();
    grid.sync();

    // ---- P2: scatter (all blocks). bbase computed locally from btot. ----
    {
        int v = (t < nbkt) ? btot[t] : 0;
        shS[t] = v;
        __syncthreads();
        for (int off = 1; off < 256; off <<= 1) {
            int u = (t >= off) ? shS[t - off] : 0;
            __syncthreads();
            shS[t] += u;
            __syncthreads();
        }
        int bbase_ex = shS[t] - v;          // exclusive scan at t
        if (t < nbkt) shA[t] = bbase_ex + blkoff[(size_t)t * NBLK + blk];
        shB[t] = 0;
        __syncthreads();
        int base = blk * ebpb;
        int end = min(base + ebpb, E);
        for (int i = base + t; i < end; i += 256) {
            int d = dst[i];
            int b = d >> 9;
            int r = atomicAdd(&shB[b], 1);
            bkt[shA[b] + r] = ((unsigned int)src[i] << 9) | (unsigned int)(d & (BS - 1));
        }
    }
    __threadfence();
    grid.sync();

    // ---- P3: csr_build (blocks 0..nbkt-1). ----
    if (blk < nbkt) {
        int b = blk;
        int v = (t < nbkt) ? btot[t] : 0;
        shS[t] = v;
        __syncthreads();
        for (int off = 1; off < 256; off <<= 1) {
            int u = (t >= off) ? shS[t - off] : 0;
            __syncthreads();
            shS[t] += u;
            __syncthreads();
        }
        shB[t] = shS[t] - v;                // exclusive bbase in shB[0..255]
        __syncthreads();
        int base = shB[b];
        int end = base + btot[b];
        __syncthreads();                    // before reusing shA/shB
        shA[t] = 0; shA[t + 256] = 0;       // cnt
        shB[t] = 0; shB[t + 256] = 0;       // rank
        __syncthreads();
        for (int i = base + t; i < end; i += 256)
            atomicAdd(&shA[bkt[i] & (BS - 1)], 1);
        __syncthreads();
        int i0 = 2 * t, i1 = 2 * t + 1;
        int v0 = shA[i0], v1 = shA[i1];
        int pair = v0 + v1;
        shS[t] = pair;
        __syncthreads();
        for (int off = 1; off < 256; off <<= 1) {
            int u = (t >= off) ? shS[t - off] : 0;
            __syncthreads();
            shS[t] += u;
            __syncthreads();
        }
        int ex = shS[t] - pair;
        __syncthreads();
        shA[i0] = ex;
        shA[i1] = ex + v0;
        __syncthreads();
        int d0 = (b << 9) + i0;
        if (d0 <= N) offsets[d0] = base + shA[i0];
        int d1 = (b << 9) + i1;
        if (d1 <= N) offsets[d1] = base + shA[i1];
        for (int i = base + t; i < end; i += 256) {
            unsigned int v2 = bkt[i];
            int dl = v2 & (BS - 1);
            int r = atomicAdd(&shB[dl], 1);
            csr[base + shA[dl] + r] = (int)(v2 >> 9);
        }
    }
}

// consume one node from a 6-slot register buffer (+tail fallback), reduce,
// self term, store row into wave-private LDS. kk must be a compile-time
// constant (unrolled caller) so idxa[kk]/buf[j] stay register-resident.
#define CONSUME_NODE(kk, dgv, e0v, buf, sf) { \
    float ax = 0.f, ay = 0.f, az = 0.f, aw = 0.f; \
    _Pragma("unroll") \
    for (int j = 0; j < 6; ++j) { \
        if (g + 4 * j < (dgv)) { \
            ax += h2f_lo(buf[j].x); ay += h2f_hi(buf[j].x); \
            az += h2f_lo(buf[j].y); aw += h2f_hi(buf[j].y); } } \
    if ((dgv) > 24) {                   /* rare tail (Poisson-12, ~0.1%) */ \
        int dc_ = min((dgv), 64); \
        for (int j = 24 + g; j < dc_; j += 4) { \
            int s_ = __shfl(idxa[kk], j, 64); \
            uint2 v_ = hp2[(size_t)s_ * 16 + sl]; \
            ax += h2f_lo(v_.x); ay += h2f_hi(v_.x); \
            az += h2f_lo(v_.y); aw += h2f_hi(v_.y); } \
        for (int j = 64 + g; j < (dgv); j += 4) {   /* astronomically rare */ \
            int s_ = csr[(e0v) + j]; \
            uint2 v_ = hp2[(size_t)s_ * 16 + sl]; \
            ax += h2f_lo(v_.x); ay += h2f_hi(v_.x); \
            az += h2f_lo(v_.y); aw += h2f_hi(v_.y); } } \
    ax += __shfl_xor(ax, 16, 64); ax += __shfl_xor(ax, 32, 64); \
    ay += __shfl_xor(ay, 16, 64); ay += __shfl_xor(ay, 32, 64); \
    az += __shfl_xor(az, 16, 64); az += __shfl_xor(az, 32, 64); \
    aw += __shfl_xor(aw, 16, 64); aw += __shfl_xor(aw, 32, 64); \
    if (tile * 16 + (kk) < N) { \
        ax = fmaf(eps1, h2f_lo(sf.x), ax); ay = fmaf(eps1, h2f_hi(sf.x), ay); \
        az = fmaf(eps1, h2f_lo(sf.y), az); aw = fmaf(eps1, h2f_hi(sf.y), aw); } \
    if (g == 0) { \
        float4 r4_; r4_.x = ax; r4_.y = ay; r4_.z = az; r4_.w = aw; \
        *(float4*)&myrows[(kk) * 64 + sl * 4] = r4_; } }

// Fused GIN layer, R18 (verbatim): wave = 16-node tile (autonomous).
// 16 idx loads upfront; 8 flat batches of 2 nodes; MFMA epilogue.
__global__ __launch_bounds__(256, 4) void layer_kernel(
        const ushort_t* __restrict__ hin, ushort_t* __restrict__ hout,
        const int* __restrict__ offsets, const int* __restrict__ csr,
        const ushort_t* __restrict__ wt_hi, const ushort_t* __restrict__ wt_lo,
        const float* __restrict__ gin_b, const float* __restrict__ eps_arr,
        int layer, int N, int E) {
    __shared__ float rows[4 * 16 * 64];   // 16KB: 4 waves x 16 nodes x 64 f32
    int t = threadIdx.x;
    int wv = t >> 6, lane = t & 63;
    int tile = blockIdx.x * 4 + wv;
    if (tile * 16 >= N) return;           // waves independent
    float* myrows = rows + wv * 16 * 64;
    const uint2* hp2 = (const uint2*)hin;
    float eps1 = 1.0f + eps_arr[layer];

    int g  = lane >> 4;    // edge group 0..3
    int sl = lane & 15;    // uint2 slot (dims 4sl..4sl+3)

    // one coalesced load covers all 17 offsets for this tile
    int off_l = offsets[min(tile * 16 + lane, N)];
    int e0a[17];
    #pragma unroll
    for (int k = 0; k < 17; ++k)
        e0a[k] = __builtin_amdgcn_readlane(off_l, k);

    // all 16 idx loads issued upfront: independent, clamped (deterministic),
    // masked at the select (which the compiler may sink -- loads stay early).
    int idxa[16];
    #pragma unroll
    for (int k = 0; k < 16; ++k) {
        int dg_ = e0a[k + 1] - e0a[k];
        int v_ = csr[min(e0a[k] + lane, E - 1)];
        idxa[k] = (lane < dg_) ? v_ : 0;
    }

    // 8 batches x 2 nodes: all 14 loads textually before any consumption.
    #pragma unroll
    for (int kb = 0; kb < 8; ++kb) {
        const int k = kb * 2;
        int e0A = e0a[k],     dgA = e0a[k + 1] - e0a[k];
        int e0B = e0a[k + 1], dgB = e0a[k + 2] - e0a[k + 1];
        uint2 b[6], c[6];
        #pragma unroll
        for (int j = 0; j < 6; ++j) {
            int p = g + 4 * j;
            int s = (p < dgA) ? __shfl(idxa[k], p, 64) : 0;
            b[j] = hp2[(size_t)s * 16 + sl];          // masked -> row 0 (L1)
        }
        #pragma unroll
        for (int j = 0; j < 6; ++j) {
            int p = g + 4 * j;
            int s = (p < dgB) ? __shfl(idxa[k + 1], p, 64) : 0;
            c[j] = hp2[(size_t)s * 16 + sl];
        }
        uint2 sfA = hp2[(size_t)min(tile * 16 + k,     N - 1) * 16 + sl];
        uint2 sfB = hp2[(size_t)min(tile * 16 + k + 1, N - 1) * 16 + sl];
        __builtin_amdgcn_sched_barrier(0);   // pin: loads above, consume below
        CONSUME_NODE(k,     dgA, e0A, b, sfA)
        CONSUME_NODE(k + 1, dgB, e0B, c, sfB)
    }
    // intra-wave LDS ordering: compiler emits lgkmcnt before reads; no barrier.

    int c2 = lane & 15;    // node within tile / n-index
    int q  = lane >> 4;    // quad
    int node16 = tile * 16 + c2;

    const ushort_t* Whi = wt_hi + layer * 4096;
    const ushort_t* Wlo = wt_lo + layer * 4096;
    const float*    bl  = gin_b + layer * 64;

    v8bf bhi[2], blo2[2];
    #pragma unroll
    for (int kt = 0; kt < 2; ++kt) {
        float4 f0 = *(float4*)&myrows[c2 * 64 + kt * 32 + q * 8];
        float4 f1 = *(float4*)&myrows[c2 * 64 + kt * 32 + q * 8 + 4];
        float xs[8] = {f0.x, f0.y, f0.z, f0.w, f1.x, f1.y, f1.z, f1.w};
        #pragma unroll
        for (int j = 0; j < 8; ++j) {
            __bf16 h = (__bf16)xs[j];
            bhi[kt][j] = h;
            blo2[kt][j] = (__bf16)(xs[j] - (float)h);
        }
    }

    #pragma unroll
    for (int mt = 0; mt < 4; ++mt) {
        v4f acc = {0.f, 0.f, 0.f, 0.f};
        #pragma unroll
        for (int kt = 0; kt < 2; ++kt) {
            int dim = mt * 16 + c2;
            size_t off = (size_t)dim * 64 + kt * 32 + q * 8;
            v8bf ah = __builtin_bit_cast(v8bf, *(const uint4*)(Whi + off));
            v8bf al = __builtin_bit_cast(v8bf, *(const uint4*)(Wlo + off));
            acc = __builtin_amdgcn_mfma_f32_16x16x32_bf16(ah, bhi[kt],  acc, 0, 0, 0);
            acc = __builtin_amdgcn_mfma_f32_16x16x32_bf16(ah, blo2[kt], acc, 0, 0, 0);
            acc = __builtin_amdgcn_mfma_f32_16x16x32_bf16(al, bhi[kt],  acc, 0, 0, 0);
        }
        float4 bv = ((const float4*)(bl + mt * 16))[q];
        float o0 = fmaxf(acc[0] + bv.x, 0.f);
        float o1 = fmaxf(acc[1] + bv.y, 0.f);
        float o2 = fmaxf(acc[2] + bv.z, 0.f);
        float o3 = fmaxf(acc[3] + bv.w, 0.f);
        uint2 pk;
        pk.x = f2h(o0) | (f2h(o1) << 16);
        pk.y = f2h(o2) | (f2h(o3) << 16);
        if (node16 < N)
            *(uint2*)(hout + (size_t)node16 * 64 + mt * 16 + q * 4) = pk;
    }
}

// Phase 1: dense partials, no atomics, VECTORIZED (uint2 = 4 dims / lane,
// 4 nodes per wave-iteration, shfl_xor cross-node reduce).
__global__ __launch_bounds__(192) void readout_part_kernel(
        const ushort_t* __restrict__ H, const int* __restrict__ gids,
        float* __restrict__ gpart, int N) {
    int graph = blockIdx.x / SPLIT;
    int sp    = blockIdx.x % SPLIT;
    int lo = 0, hi = N;
    while (lo < hi) { int mid = (lo + hi) >> 1; if (gids[mid] < graph) lo = mid + 1; else hi = mid; }
    int start = lo;
    int lo2 = start, hi2 = N;
    while (lo2 < hi2) { int mid = (lo2 + hi2) >> 1; if (gids[mid] < graph + 1) lo2 = mid + 1; else hi2 = mid; }
    int end = lo2;
    int t = threadIdx.x;            // 0..191: 3 waves, wave = layer l
    int l = t >> 6, lane = t & 63;
    int nd  = lane >> 4;            // node-phase 0..3
    int slp = lane & 15;            // uint2 slot (dims 4slp..4slp+3)
    float a0 = 0.f, a1 = 0.f, a2 = 0.f, a3 = 0.f;
    int cnt = end - start;
    if (cnt > 0) {
        int per = (cnt + SPLIT - 1) / SPLIT;
        int cs = start + sp * per;
        int ce = min(cs + per, end);
        const uint2* Hl = (const uint2*)(H + (size_t)l * N * 64);
        for (int n = cs + nd; n < ce; n += 4) {
            uint2 v = Hl[(size_t)n * 16 + slp];
            a0 += h2f_lo(v.x); a1 += h2f_hi(v.x);
            a2 += h2f_lo(v.y); a3 += h2f_hi(v.y);
        }
    }
    a0 += __shfl_xor(a0, 16, 64); a0 += __shfl_xor(a0, 32, 64);
    a1 += __shfl_xor(a1, 16, 64); a1 += __shfl_xor(a1, 32, 64);
    a2 += __shfl_xor(a2, 16, 64); a2 += __shfl_xor(a2, 32, 64);
    a3 += __shfl_xor(a3, 16, 64); a3 += __shfl_xor(a3, 32, 64);
    if (lane < 16) {
        float4 r4; r4.x = a0; r4.y = a1; r4.z = a2; r4.w = a3;
        *(float4*)&gpart[(size_t)(graph * SPLIT + sp) * 192 + l * 64 + slp * 4] = r4;
    }
}

// Phase 2 fused with MLP: sum 16 partials -> gr, then 2-layer MLP.
__global__ __launch_bounds__(192) void mlp_kernel(
        const float* __restrict__ gpart,
        const float* __restrict__ W1, const float* __restrict__ b1,
        const float* __restrict__ W2, const float* __restrict__ b2,
        float* __restrict__ out) {
    __shared__ float gr[192];
    __shared__ float hid[128];
    int graph = blockIdx.x;
    int t = threadIdx.x;
    float a = 0.f;
    #pragma unroll
    for (int sp = 0; sp < SPLIT; ++sp)
        a += gpart[(size_t)(graph * SPLIT + sp) * 192 + t];
    gr[t] = a;
    __syncthreads();
    if (t < 128) {
        float s = b1[t];
        for (int k = 0; k < 192; ++k) s = fmaf(gr[k], W1[k * 128 + t], s);
        hid[t] = fmaxf(s, 0.0f);
    }
    __syncthreads();
    if (t < 32) {
        float s = b2[t];
        for (int k = 0; k < 128; ++k) s = fmaf(hid[k], W2[k * 32 + t], s);
        out[graph * 32 + t] = s;
    }
}

extern "C" void kernel_launch(void* const* d_in, const int* in_sizes, int n_in,
                              void* d_out, int out_size, void* d_ws, size_t ws_size,
                              hipStream_t stream) {
    const float* x     = (const float*)d_in[0];
    const float* gin_W = (const float*)d_in[1];
    const float* gin_b = (const float*)d_in[2];
    const float* eps   = (const float*)d_in[3];
    const float* r_W1  = (const float*)d_in[4];
    const float* r_b1  = (const float*)d_in[5];
    const float* r_W2  = (const float*)d_in[6];
    const float* r_b2  = (const float*)d_in[7];
    const int*   src   = (const int*)d_in[8];
    const int*   dst   = (const int*)d_in[9];
    const int*   gids  = (const int*)d_in[10];

    int N = in_sizes[0] / 64;       // 100000
    int E = in_sizes[8];            // 1200000
    int B = out_size / 32;          // 256

    int nbkt = (N + BS - 1) / BS;   // 196 (<= 256)
    int ebpb = (E + NBLK - 1) / NBLK;
    int n4 = N * 64 / 4;
    int wtotal = 3 * 4096;

    // workspace layout (4B words), all regions fully written before read:
    //   gpart[B*SPLIT*192]
    //   cnt2d[NBLK*nbkt] | blkoff[nbkt*NBLK] | btot[nbkt] | bbase[nbkt+1]
    //   offsets[N+1] | bkt[E] | csr[E] | pad
    //   xh[N*64 f16] | H[3*N*64 f16] | whi[3*4096] | wlo[3*4096]
    int* ws       = (int*)d_ws;
    float* gpart  = (float*)ws;
    int* cnt2d    = ws + (size_t)B * SPLIT * 192;
    int* blkoff   = cnt2d + (size_t)NBLK * nbkt;
    int* btot     = blkoff + (size_t)nbkt * NBLK;
    int* bbase    = btot + nbkt;            // unused (kept for layout)
    int* offsets  = bbase + (nbkt + 1);
    unsigned int* bkt = (unsigned int*)(offsets + (N + 1));
    int* csr      = (int*)(bkt + E);
    size_t w      = (size_t)(csr + E - ws);
    w = (w + 15) & ~(size_t)15;     // 64B align
    ushort_t* xh  = (ushort_t*)(ws + w);
    ushort_t* H   = xh + (size_t)N * 64;
    ushort_t* whi = H + 3 * (size_t)N * 64;
    ushort_t* wlo = whi + 3 * 4096;

    {
        void* args[] = {
            (void*)&src, (void*)&dst, (void*)&x, (void*)&gin_W,
            (void*)&cnt2d, (void*)&btot, (void*)&blkoff, (void*)&bkt,
            (void*)&csr, (void*)&offsets, (void*)&xh, (void*)&whi, (void*)&wlo,
            (void*)&N, (void*)&E, (void*)&nbkt, (void*)&ebpb,
            (void*)&n4, (void*)&wtotal };
        hipLaunchCooperativeKernel((void*)prep_coop_kernel,
                                   dim3(NBLK), dim3(256), args, 0, stream);
    }

    int lbk = (N + 63) / 64;        // 4 tiles (waves) of 16 nodes per block
    ushort_t* H0 = H;
    ushort_t* H1 = H + (size_t)N * 64;
    ushort_t* H2 = H + 2 * (size_t)N * 64;

    layer_kernel<<<lbk, 256, 0, stream>>>(xh, H0, offsets, csr, whi, wlo, gin_b, eps, 0, N, E);
    layer_kernel<<<lbk, 256, 0, stream>>>(H0, H1, offsets, csr, whi, wlo, gin_b, eps, 1, N, E);
    layer_kernel<<<lbk, 256, 0, stream>>>(H1, H2, offsets, csr, whi, wlo, gin_b, eps, 2, N, E);

    readout_part_kernel<<<B * SPLIT, 192, 0, stream>>>(H, gids, gpart, N);
    mlp_kernel<<<B, 192, 0, stream>>>(gpart, r_W1, r_b1, r_W2, r_b2, (float*)d_out);
}

// Round 8
// 312.786 us; speedup vs baseline: 2.0428x; 2.0428x over previous
//
#include <hip/hip_runtime.h>

// GIN: 3 layers of {agg = scatter_sum(h[src] -> dst); h = relu(((1+eps)h + agg) @ W + b)}
// then per-graph segment-sum readout (graph_ids sorted) -> 2-layer MLP.
//
// R21: revert R20's cooperative fusion (grid.sync cost ~100us/barrier:
//      prep_coop 376us @ VALUBusy 0.5%). Back to discrete launches, but the
//      prep chain is shortened:
//      (a) colscan + cnt2d ELIMINATED: count phase does one global
//          atomicAdd(&btot[b], lcnt[b]) per (block,bucket) (~100K atomics,
//          196 addresses); scatter reserves per-bucket ranges via
//          lbase[b] = atomicAdd(&cursor[b], lcnt[b]) -- order within a
//          bucket is irrelevant for CSR. Saves 1 kernel + 800KB strided
//          cnt2d traffic. btot/cursor zeroed by a 784B hipMemsetAsync
//          (graph-capturable memset node).
//      (b) readout_part vectorized (from R20, passed): uint2 loads,
//          4 nodes/wave-iter, shfl_xor cross-node reduce.
//      (c) layer_kernel = R18 verbatim (50.5us; ILP closed R14-R18, TLP
//          closed R19: more waves -> BW dropped, gather path saturated).
// R18: flat-batch gather (best layer). R13: uniform-trip gather.
// R12: merged pre. R10: fused layer + atomic-free readout. R9: bucketed CSR.
// R7: f16 H. R5: MFMA bf16 hi/lo 3-product gemm.

#define SPLIT 16
#define NBLK 512     // edge chunks for bucket build
#define BS 512       // nodes per bucket (pow2)

typedef unsigned short ushort_t;
typedef __bf16 v8bf __attribute__((ext_vector_type(8)));
typedef float v4f __attribute__((ext_vector_type(4)));

__device__ __forceinline__ float h2f_lo(unsigned int v) {
    return (float)__builtin_bit_cast(_Float16, (unsigned short)(v & 0xffffu));
}
__device__ __forceinline__ float h2f_hi(unsigned int v) {
    return (float)__builtin_bit_cast(_Float16, (unsigned short)(v >> 16));
}
__device__ __forceinline__ unsigned int f2h(float f) {
    return (unsigned int)__builtin_bit_cast(unsigned short, (_Float16)f);
}

// Merged: bucket_count->btot (blocks 0..NBLK-1) | cast | Wprep.
__global__ __launch_bounds__(256) void pre_kernel(
        const int* __restrict__ dst, int* __restrict__ btot,
        int E, int nbkt, int ebpb,
        const float* __restrict__ x, ushort_t* __restrict__ xh, int n4, int castBlocks,
        const float* __restrict__ W, ushort_t* __restrict__ whi,
        ushort_t* __restrict__ wlo, int wtotal) {
    __shared__ int lcnt[256];
    int t = threadIdx.x;
    int blk = blockIdx.x;
    if (blk < NBLK) {
        lcnt[t] = 0;
        __syncthreads();
        int base = blk * ebpb;
        int end = min(base + ebpb, E);
        for (int i = base + t; i < end; i += 256)
            atomicAdd(&lcnt[dst[i] >> 9], 1);
        __syncthreads();
        if (t < nbkt && lcnt[t]) atomicAdd(&btot[t], lcnt[t]);
    } else if (blk < NBLK + castBlocks) {
        int i = (blk - NBLK) * 256 + t;
        if (i < n4) {
            float4 v = ((const float4*)x)[i];
            uint2 p;
            p.x = f2h(v.x) | (f2h(v.y) << 16);
            p.y = f2h(v.z) | (f2h(v.w) << 16);
            ((uint2*)xh)[i] = p;
        }
    } else {
        int i = (blk - NBLK - castBlocks) * 256 + t;
        if (i < wtotal) {
            int l = i >> 12, r = i & 4095;
            int n = r >> 6, k = r & 63;
            float w = W[l * 4096 + k * 64 + n];
            __bf16 h = (__bf16)w;
            float rem = w - (float)h;
            whi[i] = __builtin_bit_cast(ushort_t, h);
            wlo[i] = __builtin_bit_cast(ushort_t, (__bf16)rem);
        }
    }
}

// B: scan btot[nbkt] -> bbase[nbkt+1]; cursor = bbase; offsets[N]=E.
__global__ __launch_bounds__(256) void bucket_base_kernel(
        const int* __restrict__ btot, int* __restrict__ bbase,
        int* __restrict__ cursor, int* __restrict__ offsets,
        int nbkt, int N, int E) {
    __shared__ int sh[256];
    int t = threadIdx.x;
    int v = (t < nbkt) ? btot[t] : 0;
    sh[t] = v;
    __syncthreads();
    for (int off = 1; off < 256; off <<= 1) {
        int u = (t >= off) ? sh[t - off] : 0;
        __syncthreads();
        sh[t] += u;
        __syncthreads();
    }
    int ex = sh[t] - v;                 // exclusive scan
    if (t < nbkt) { bbase[t] = ex; cursor[t] = ex; }
    if (t == 0) { bbase[nbkt] = E; offsets[N] = E; }
}

// C: scatter edges into bucket regions as packed (src<<9)|d_local.
// Per-block range reservation: lbase[b] = atomicAdd(&cursor[b], lcnt[b]).
__global__ __launch_bounds__(256) void bucket_scatter_kernel(
        const int* __restrict__ src, const int* __restrict__ dst,
        int* __restrict__ cursor, unsigned int* __restrict__ bkt,
        int E, int nbkt, int ebpb) {
    __shared__ int lcnt[256];
    __shared__ int lbase[256];
    __shared__ int lrank[256];
    int t = threadIdx.x;
    lcnt[t] = 0; lrank[t] = 0;
    __syncthreads();
    int base = blockIdx.x * ebpb;
    int end = min(base + ebpb, E);
    for (int i = base + t; i < end; i += 256)
        atomicAdd(&lcnt[dst[i] >> 9], 1);       // chunk fits L1 -> cheap re-read
    __syncthreads();
    if (t < nbkt && lcnt[t]) lbase[t] = atomicAdd(&cursor[t], lcnt[t]);
    __syncthreads();
    for (int i = base + t; i < end; i += 256) {
        int d = dst[i];
        int b = d >> 9;
        int r = atomicAdd(&lrank[b], 1);
        bkt[lbase[b] + r] = ((unsigned int)src[i] << 9) | (unsigned int)(d & (BS - 1));
    }
}

// D: block b = bucket b. LDS hist + scan -> offsets + csr (LDS atomics only).
__global__ __launch_bounds__(256) void csr_build_kernel(
        const unsigned int* __restrict__ bkt, const int* __restrict__ bbase,
        int* __restrict__ offsets, int* __restrict__ csr, int N, int nbkt) {
    __shared__ int cnt[BS];
    __shared__ int rank[BS];
    __shared__ int sh[256];
    int b = blockIdx.x, t = threadIdx.x;
    cnt[t] = 0; cnt[t + 256] = 0;
    rank[t] = 0; rank[t + 256] = 0;
    __syncthreads();
    int base = bbase[b], end = bbase[b + 1];
    for (int i = base + t; i < end; i += 256)
        atomicAdd(&cnt[bkt[i] & (BS - 1)], 1);
    __syncthreads();
    int i0 = 2 * t, i1 = 2 * t + 1;
    int v0 = cnt[i0], v1 = cnt[i1];
    int pair = v0 + v1;
    sh[t] = pair;
    __syncthreads();
    for (int off = 1; off < 256; off <<= 1) {
        int u = (t >= off) ? sh[t - off] : 0;
        __syncthreads();
        sh[t] += u;
        __syncthreads();
    }
    int ex = sh[t] - pair;
    __syncthreads();
    cnt[i0] = ex;
    cnt[i1] = ex + v0;
    __syncthreads();
    int d0 = (b << 9) + i0;
    if (d0 <= N) offsets[d0] = base + cnt[i0];
    int d1 = (b << 9) + i1;
    if (d1 <= N) offsets[d1] = base + cnt[i1];
    for (int i = base + t; i < end; i += 256) {
        unsigned int v = bkt[i];
        int dl = v & (BS - 1);
        int r = atomicAdd(&rank[dl], 1);
        csr[base + cnt[dl] + r] = (int)(v >> 9);
    }
}

// consume one node from a 6-slot register buffer (+tail fallback), reduce,
// self term, store row into wave-private LDS. kk must be a compile-time
// constant (unrolled caller) so idxa[kk]/buf[j] stay register-resident.
#define CONSUME_NODE(kk, dgv, e0v, buf, sf) { \
    float ax = 0.f, ay = 0.f, az = 0.f, aw = 0.f; \
    _Pragma("unroll") \
    for (int j = 0; j < 6; ++j) { \
        if (g + 4 * j < (dgv)) { \
            ax += h2f_lo(buf[j].x); ay += h2f_hi(buf[j].x); \
            az += h2f_lo(buf[j].y); aw += h2f_hi(buf[j].y); } } \
    if ((dgv) > 24) {                   /* rare tail (Poisson-12, ~0.1%) */ \
        int dc_ = min((dgv), 64); \
        for (int j = 24 + g; j < dc_; j += 4) { \
            int s_ = __shfl(idxa[kk], j, 64); \
            uint2 v_ = hp2[(size_t)s_ * 16 + sl]; \
            ax += h2f_lo(v_.x); ay += h2f_hi(v_.x); \
            az += h2f_lo(v_.y); aw += h2f_hi(v_.y); } \
        for (int j = 64 + g; j < (dgv); j += 4) {   /* astronomically rare */ \
            int s_ = csr[(e0v) + j]; \
            uint2 v_ = hp2[(size_t)s_ * 16 + sl]; \
            ax += h2f_lo(v_.x); ay += h2f_hi(v_.x); \
            az += h2f_lo(v_.y); aw += h2f_hi(v_.y); } } \
    ax += __shfl_xor(ax, 16, 64); ax += __shfl_xor(ax, 32, 64); \
    ay += __shfl_xor(ay, 16, 64); ay += __shfl_xor(ay, 32, 64); \
    az += __shfl_xor(az, 16, 64); az += __shfl_xor(az, 32, 64); \
    aw += __shfl_xor(aw, 16, 64); aw += __shfl_xor(aw, 32, 64); \
    if (tile * 16 + (kk) < N) { \
        ax = fmaf(eps1, h2f_lo(sf.x), ax); ay = fmaf(eps1, h2f_hi(sf.x), ay); \
        az = fmaf(eps1, h2f_lo(sf.y), az); aw = fmaf(eps1, h2f_hi(sf.y), aw); } \
    if (g == 0) { \
        float4 r4_; r4_.x = ax; r4_.y = ay; r4_.z = az; r4_.w = aw; \
        *(float4*)&myrows[(kk) * 64 + sl * 4] = r4_; } }

// Fused GIN layer, R18 (verbatim): wave = 16-node tile (autonomous).
// 16 idx loads upfront; 8 flat batches of 2 nodes; MFMA epilogue.
__global__ __launch_bounds__(256, 4) void layer_kernel(
        const ushort_t* __restrict__ hin, ushort_t* __restrict__ hout,
        const int* __restrict__ offsets, const int* __restrict__ csr,
        const ushort_t* __restrict__ wt_hi, const ushort_t* __restrict__ wt_lo,
        const float* __restrict__ gin_b, const float* __restrict__ eps_arr,
        int layer, int N, int E) {
    __shared__ float rows[4 * 16 * 64];   // 16KB: 4 waves x 16 nodes x 64 f32
    int t = threadIdx.x;
    int wv = t >> 6, lane = t & 63;
    int tile = blockIdx.x * 4 + wv;
    if (tile * 16 >= N) return;           // waves independent
    float* myrows = rows + wv * 16 * 64;
    const uint2* hp2 = (const uint2*)hin;
    float eps1 = 1.0f + eps_arr[layer];

    int g  = lane >> 4;    // edge group 0..3
    int sl = lane & 15;    // uint2 slot (dims 4sl..4sl+3)

    // one coalesced load covers all 17 offsets for this tile
    int off_l = offsets[min(tile * 16 + lane, N)];
    int e0a[17];
    #pragma unroll
    for (int k = 0; k < 17; ++k)
        e0a[k] = __builtin_amdgcn_readlane(off_l, k);

    // all 16 idx loads issued upfront: independent, clamped (deterministic),
    // masked at the select (which the compiler may sink -- loads stay early).
    int idxa[16];
    #pragma unroll
    for (int k = 0; k < 16; ++k) {
        int dg_ = e0a[k + 1] - e0a[k];
        int v_ = csr[min(e0a[k] + lane, E - 1)];
        idxa[k] = (lane < dg_) ? v_ : 0;
    }

    // 8 batches x 2 nodes: all 14 loads textually before any consumption.
    #pragma unroll
    for (int kb = 0; kb < 8; ++kb) {
        const int k = kb * 2;
        int e0A = e0a[k],     dgA = e0a[k + 1] - e0a[k];
        int e0B = e0a[k + 1], dgB = e0a[k + 2] - e0a[k + 1];
        uint2 b[6], c[6];
        #pragma unroll
        for (int j = 0; j < 6; ++j) {
            int p = g + 4 * j;
            int s = (p < dgA) ? __shfl(idxa[k], p, 64) : 0;
            b[j] = hp2[(size_t)s * 16 + sl];          // masked -> row 0 (L1)
        }
        #pragma unroll
        for (int j = 0; j < 6; ++j) {
            int p = g + 4 * j;
            int s = (p < dgB) ? __shfl(idxa[k + 1], p, 64) : 0;
            c[j] = hp2[(size_t)s * 16 + sl];
        }
        uint2 sfA = hp2[(size_t)min(tile * 16 + k,     N - 1) * 16 + sl];
        uint2 sfB = hp2[(size_t)min(tile * 16 + k + 1, N - 1) * 16 + sl];
        __builtin_amdgcn_sched_barrier(0);   // pin: loads above, consume below
        CONSUME_NODE(k,     dgA, e0A, b, sfA)
        CONSUME_NODE(k + 1, dgB, e0B, c, sfB)
    }
    // intra-wave LDS ordering: compiler emits lgkmcnt before reads; no barrier.

    int c2 = lane & 15;    // node within tile / n-index
    int q  = lane >> 4;    // quad
    int node16 = tile * 16 + c2;

    const ushort_t* Whi = wt_hi + layer * 4096;
    const ushort_t* Wlo = wt_lo + layer * 4096;
    const float*    bl  = gin_b + layer * 64;

    v8bf bhi[2], blo2[2];
    #pragma unroll
    for (int kt = 0; kt < 2; ++kt) {
        float4 f0 = *(float4*)&myrows[c2 * 64 + kt * 32 + q * 8];
        float4 f1 = *(float4*)&myrows[c2 * 64 + kt * 32 + q * 8 + 4];
        float xs[8] = {f0.x, f0.y, f0.z, f0.w, f1.x, f1.y, f1.z, f1.w};
        #pragma unroll
        for (int j = 0; j < 8; ++j) {
            __bf16 h = (__bf16)xs[j];
            bhi[kt][j] = h;
            blo2[kt][j] = (__bf16)(xs[j] - (float)h);
        }
    }

    #pragma unroll
    for (int mt = 0; mt < 4; ++mt) {
        v4f acc = {0.f, 0.f, 0.f, 0.f};
        #pragma unroll
        for (int kt = 0; kt < 2; ++kt) {
            int dim = mt * 16 + c2;
            size_t off = (size_t)dim * 64 + kt * 32 + q * 8;
            v8bf ah = __builtin_bit_cast(v8bf, *(const uint4*)(Whi + off));
            v8bf al = __builtin_bit_cast(v8bf, *(const uint4*)(Wlo + off));
            acc = __builtin_amdgcn_mfma_f32_16x16x32_bf16(ah, bhi[kt],  acc, 0, 0, 0);
            acc = __builtin_amdgcn_mfma_f32_16x16x32_bf16(ah, blo2[kt], acc, 0, 0, 0);
            acc = __builtin_amdgcn_mfma_f32_16x16x32_bf16(al, bhi[kt],  acc, 0, 0, 0);
        }
        float4 bv = ((const float4*)(bl + mt * 16))[q];
        float o0 = fmaxf(acc[0] + bv.x, 0.f);
        float o1 = fmaxf(acc[1] + bv.y, 0.f);
        float o2 = fmaxf(acc[2] + bv.z, 0.f);
        float o3 = fmaxf(acc[3] + bv.w, 0.f);
        uint2 pk;
        pk.x = f2h(o0) | (f2h(o1) << 16);
        pk.y = f2h(o2) | (f2h(o3) << 16);
        if (node16 < N)
            *(uint2*)(hout + (size_t)node16 * 64 + mt * 16 + q * 4) = pk;
    }
}

// Phase 1: dense partials, no atomics, VECTORIZED (uint2 = 4 dims / lane,
// 4 nodes per wave-iteration, shfl_xor cross-node reduce).
__global__ __launch_bounds__(192) void readout_part_kernel(
        const ushort_t* __restrict__ H, const int* __restrict__ gids,
        float* __restrict__ gpart, int N) {
    int graph = blockIdx.x / SPLIT;
    int sp    = blockIdx.x % SPLIT;
    int lo = 0, hi = N;
    while (lo < hi) { int mid = (lo + hi) >> 1; if (gids[mid] < graph) lo = mid + 1; else hi = mid; }
    int start = lo;
    int lo2 = start, hi2 = N;
    while (lo2 < hi2) { int mid = (lo2 + hi2) >> 1; if (gids[mid] < graph + 1) lo2 = mid + 1; else hi2 = mid; }
    int end = lo2;
    int t = threadIdx.x;            // 0..191: 3 waves, wave = layer l
    int l = t >> 6, lane = t & 63;
    int nd  = lane >> 4;            // node-phase 0..3
    int slp = lane & 15;            // uint2 slot (dims 4slp..4slp+3)
    float a0 = 0.f, a1 = 0.f, a2 = 0.f, a3 = 0.f;
    int cnt = end - start;
    if (cnt > 0) {
        int per = (cnt + SPLIT - 1) / SPLIT;
        int cs = start + sp * per;
        int ce = min(cs + per, end);
        const uint2* Hl = (const uint2*)(H + (size_t)l * N * 64);
        for (int n = cs + nd; n < ce; n += 4) {
            uint2 v = Hl[(size_t)n * 16 + slp];
            a0 += h2f_lo(v.x); a1 += h2f_hi(v.x);
            a2 += h2f_lo(v.y); a3 += h2f_hi(v.y);
        }
    }
    a0 += __shfl_xor(a0, 16, 64); a0 += __shfl_xor(a0, 32, 64);
    a1 += __shfl_xor(a1, 16, 64); a1 += __shfl_xor(a1, 32, 64);
    a2 += __shfl_xor(a2, 16, 64); a2 += __shfl_xor(a2, 32, 64);
    a3 += __shfl_xor(a3, 16, 64); a3 += __shfl_xor(a3, 32, 64);
    if (lane < 16) {
        float4 r4; r4.x = a0; r4.y = a1; r4.z = a2; r4.w = a3;
        *(float4*)&gpart[(size_t)(graph * SPLIT + sp) * 192 + l * 64 + slp * 4] = r4;
    }
}

// Phase 2 fused with MLP: sum 16 partials -> gr, then 2-layer MLP.
__global__ __launch_bounds__(192) void mlp_kernel(
        const float* __restrict__ gpart,
        const float* __restrict__ W1, const float* __restrict__ b1,
        const float* __restrict__ W2, const float* __restrict__ b2,
        float* __restrict__ out) {
    __shared__ float gr[192];
    __shared__ float hid[128];
    int graph = blockIdx.x;
    int t = threadIdx.x;
    float a = 0.f;
    #pragma unroll
    for (int sp = 0; sp < SPLIT; ++sp)
        a += gpart[(size_t)(graph * SPLIT + sp) * 192 + t];
    gr[t] = a;
    __syncthreads();
    if (t < 128) {
        float s = b1[t];
        for (int k = 0; k < 192; ++k) s = fmaf(gr[k], W1[k * 128 + t], s);
        hid[t] = fmaxf(s, 0.0f);
    }
    __syncthreads();
    if (t < 32) {
        float s = b2[t];
        for (int k = 0; k < 128; ++k) s = fmaf(hid[k], W2[k * 32 + t], s);
        out[graph * 32 + t] = s;
    }
}

extern "C" void kernel_launch(void* const* d_in, const int* in_sizes, int n_in,
                              void* d_out, int out_size, void* d_ws, size_t ws_size,
                              hipStream_t stream) {
    const float* x     = (const float*)d_in[0];
    const float* gin_W = (const float*)d_in[1];
    const float* gin_b = (const float*)d_in[2];
    const float* eps   = (const float*)d_in[3];
    const float* r_W1  = (const float*)d_in[4];
    const float* r_b1  = (const float*)d_in[5];
    const float* r_W2  = (const float*)d_in[6];
    const float* r_b2  = (const float*)d_in[7];
    const int*   src   = (const int*)d_in[8];
    const int*   dst   = (const int*)d_in[9];
    const int*   gids  = (const int*)d_in[10];

    int N = in_sizes[0] / 64;       // 100000
    int E = in_sizes[8];            // 1200000
    int B = out_size / 32;          // 256

    int nbkt = (N + BS - 1) / BS;   // 196 (<= 256)
    int ebpb = (E + NBLK - 1) / NBLK;
    int n4 = N * 64 / 4;
    int castBlocks = (n4 + 255) / 256;
    int wtotal = 3 * 4096;
    int prepBlocks = (wtotal + 255) / 256;

    // workspace layout (4B words), all regions fully written before read:
    //   gpart[B*SPLIT*192]
    //   btot[nbkt] | cursor[nbkt] | bbase[nbkt+1]
    //   offsets[N+1] | bkt[E] | csr[E] | pad
    //   xh[N*64 f16] | H[3*N*64 f16] | whi[3*4096] | wlo[3*4096]
    int* ws       = (int*)d_ws;
    float* gpart  = (float*)ws;
    int* btot     = ws + (size_t)B * SPLIT * 192;
    int* cursor   = btot + nbkt;
    int* bbase    = cursor + nbkt;
    int* offsets  = bbase + (nbkt + 1);
    unsigned int* bkt = (unsigned int*)(offsets + (N + 1));
    int* csr      = (int*)(bkt + E);
    size_t w      = (size_t)(csr + E - ws);
    w = (w + 15) & ~(size_t)15;     // 64B align
    ushort_t* xh  = (ushort_t*)(ws + w);
    ushort_t* H   = xh + (size_t)N * 64;
    ushort_t* whi = H + 3 * (size_t)N * 64;
    ushort_t* wlo = whi + 3 * 4096;

    hipMemsetAsync(btot, 0, nbkt * sizeof(int), stream);   // capturable memset node
    pre_kernel<<<NBLK + castBlocks + prepBlocks, 256, 0, stream>>>(
        dst, btot, E, nbkt, ebpb, x, xh, n4, castBlocks, gin_W, whi, wlo, wtotal);
    bucket_base_kernel<<<1, 256, 0, stream>>>(btot, bbase, cursor, offsets, nbkt, N, E);
    bucket_scatter_kernel<<<NBLK, 256, 0, stream>>>(src, dst, cursor, bkt, E, nbkt, ebpb);
    csr_build_kernel<<<nbkt, 256, 0, stream>>>(bkt, bbase, offsets, csr, N, nbkt);

    int lbk = (N + 63) / 64;        // 4 tiles (waves) of 16 nodes per block
    ushort_t* H0 = H;
    ushort_t* H1 = H + (size_t)N * 64;
    ushort_t* H2 = H + 2 * (size_t)N * 64;

    layer_kernel<<<lbk, 256, 0, stream>>>(xh, H0, offsets, csr, whi, wlo, gin_b, eps, 0, N, E);
    layer_kernel<<<lbk, 256, 0, stream>>>(H0, H1, offsets, csr, whi, wlo, gin_b, eps, 1, N, E);
    layer_kernel<<<lbk, 256, 0, stream>>>(H1, H2, offsets, csr, whi, wlo, gin_b, eps, 2, N, E);

    readout_part_kernel<<<B * SPLIT, 192, 0, stream>>>(H, gids, gpart, N);
    mlp_kernel<<<B, 192, 0, stream>>>(gpart, r_W1, r_b1, r_W2, r_b2, (float*)d_out);
}

// Round 9
// 296.324 us; speedup vs baseline: 2.1563x; 1.0556x over previous
//
#include <hip/hip_runtime.h>

// GIN: 3 layers of {agg = scatter_sum(h[src] -> dst); h = relu(((1+eps)h + agg) @ W + b)}
// then per-graph segment-sum readout (graph_ids sorted) -> 2-layer MLP.
//
// R22: dispatch-count attack. Non-layer = ~163us vs ~65us of kernel work ->
//      chain is launch/gap dominated. Changes (no new sync primitives):
//      (a) SLACK buckets: fixed 8192-slot region per bucket (base = b<<13,
//          max bucket ~6500 = 21 sigma under cap). Scatter reserves ranges
//          via atomicAdd(&cnt[b], lcnt[b]) -> pre-count pass AND the
//          1-block prefix-scan kernel are eliminated. CSR kept in slack
//          layout; per-node metadata now explicit int2 (e0, deg).
//      (b) x-cast + W-prep merged into the scatter kernel (extra blocks).
//      (c) readout_part + mlp fused: block = graph, 6 waves (layer x
//          parity), uint2 loads, shfl_xor reduce, LDS combine, MLP.
//      7 dispatches total (was 10). Layer kernel = R18 except int2
//      metadata decode (gather + MFMA epilogue untouched).
// R21: colscan eliminated. R18: flat-batch gather (layer floor 49.7us,
//      gather path saturated: R19 occupancy 42->66% LOWERED BW).
// R13: uniform-trip gather. R10: fused layer. R9: bucketed CSR. R7: f16 H.
// R5: MFMA bf16 hi/lo 3-product gemm.

#define NBLK 512     // edge chunks for bucket build
#define BS 512       // nodes per bucket (pow2)
#define CAPSH 13     // slack region: 8192 slots per bucket

typedef unsigned short ushort_t;
typedef __bf16 v8bf __attribute__((ext_vector_type(8)));
typedef float v4f __attribute__((ext_vector_type(4)));

__device__ __forceinline__ float h2f_lo(unsigned int v) {
    return (float)__builtin_bit_cast(_Float16, (unsigned short)(v & 0xffffu));
}
__device__ __forceinline__ float h2f_hi(unsigned int v) {
    return (float)__builtin_bit_cast(_Float16, (unsigned short)(v >> 16));
}
__device__ __forceinline__ unsigned int f2h(float f) {
    return (unsigned int)__builtin_bit_cast(unsigned short, (_Float16)f);
}

// A: scatter into slack bucket regions (blocks 0..NBLK-1) | x cast | W split.
__global__ __launch_bounds__(256) void scatter_pre_kernel(
        const int* __restrict__ src, const int* __restrict__ dst,
        int* __restrict__ cnt, unsigned int* __restrict__ bkt,
        int E, int nbkt, int ebpb,
        const float* __restrict__ x, ushort_t* __restrict__ xh, int n4, int castBlocks,
        const float* __restrict__ W, ushort_t* __restrict__ whi,
        ushort_t* __restrict__ wlo, int wtotal) {
    __shared__ int lcnt[256];
    __shared__ int lbase[256];
    __shared__ int lrank[256];
    int t = threadIdx.x;
    int blk = blockIdx.x;
    if (blk < NBLK) {
        lcnt[t] = 0; lrank[t] = 0;
        __syncthreads();
        int base = blk * ebpb;
        int end = min(base + ebpb, E);
        for (int i = base + t; i < end; i += 256)
            atomicAdd(&lcnt[dst[i] >> 9], 1);       // chunk fits L1/L2: cheap re-read
        __syncthreads();
        if (t < nbkt && lcnt[t])
            lbase[t] = (t << CAPSH) + atomicAdd(&cnt[t], lcnt[t]);
        __syncthreads();
        for (int i = base + t; i < end; i += 256) {
            int d = dst[i];
            int b = d >> 9;
            int r = atomicAdd(&lrank[b], 1);
            bkt[lbase[b] + r] = ((unsigned int)src[i] << 9) | (unsigned int)(d & (BS - 1));
        }
    } else if (blk < NBLK + castBlocks) {
        int i = (blk - NBLK) * 256 + t;
        if (i < n4) {
            float4 v = ((const float4*)x)[i];
            uint2 p;
            p.x = f2h(v.x) | (f2h(v.y) << 16);
            p.y = f2h(v.z) | (f2h(v.w) << 16);
            ((uint2*)xh)[i] = p;
        }
    } else {
        int i = (blk - NBLK - castBlocks) * 256 + t;
        if (i < wtotal) {
            int l = i >> 12, r = i & 4095;
            int n = r >> 6, k = r & 63;
            float w = W[l * 4096 + k * 64 + n];
            __bf16 h = (__bf16)w;
            float rem = w - (float)h;
            whi[i] = __builtin_bit_cast(ushort_t, h);
            wlo[i] = __builtin_bit_cast(ushort_t, (__bf16)rem);
        }
    }
}

// B: block b = bucket b. LDS hist + scan -> offsets2 (e0,deg) + slack csr.
__global__ __launch_bounds__(256) void csr_build_kernel(
        const unsigned int* __restrict__ bkt, const int* __restrict__ cnt,
        int2* __restrict__ offsets2, int* __restrict__ csr, int N) {
    __shared__ int c0[BS];
    __shared__ int rk[BS];
    __shared__ int sh[256];
    int b = blockIdx.x, t = threadIdx.x;
    c0[t] = 0; c0[t + 256] = 0;
    rk[t] = 0; rk[t + 256] = 0;
    __syncthreads();
    int base = b << CAPSH;
    int cb = cnt[b];
    for (int i = t; i < cb; i += 256)
        atomicAdd(&c0[bkt[base + i] & (BS - 1)], 1);
    __syncthreads();
    int i0 = 2 * t, i1 = 2 * t + 1;
    int v0 = c0[i0], v1 = c0[i1];
    int pair = v0 + v1;
    sh[t] = pair;
    __syncthreads();
    for (int off = 1; off < 256; off <<= 1) {
        int u = (t >= off) ? sh[t - off] : 0;
        __syncthreads();
        sh[t] += u;
        __syncthreads();
    }
    int ex = sh[t] - pair;
    __syncthreads();
    c0[i0] = ex;
    c0[i1] = ex + v0;
    __syncthreads();
    int d0 = (b << 9) + i0;
    if (d0 < N) offsets2[d0] = make_int2(base + c0[i0], v0);
    int d1 = (b << 9) + i1;
    if (d1 < N) offsets2[d1] = make_int2(base + c0[i1], v1);
    for (int i = t; i < cb; i += 256) {
        unsigned int v = bkt[base + i];
        int dl = v & (BS - 1);
        int r = atomicAdd(&rk[dl], 1);
        csr[base + c0[dl] + r] = (int)(v >> 9);
    }
}

// consume one node from a 6-slot register buffer (+tail fallback), reduce,
// self term, store row into wave-private LDS. kk must be a compile-time
// constant (unrolled caller) so idxa[kk]/buf[j] stay register-resident.
#define CONSUME_NODE(kk, dgv, e0v, buf, sf) { \
    float ax = 0.f, ay = 0.f, az = 0.f, aw = 0.f; \
    _Pragma("unroll") \
    for (int j = 0; j < 6; ++j) { \
        if (g + 4 * j < (dgv)) { \
            ax += h2f_lo(buf[j].x); ay += h2f_hi(buf[j].x); \
            az += h2f_lo(buf[j].y); aw += h2f_hi(buf[j].y); } } \
    if ((dgv) > 24) {                   /* rare tail (Poisson-12, ~0.1%) */ \
        int dc_ = min((dgv), 64); \
        for (int j = 24 + g; j < dc_; j += 4) { \
            int s_ = __shfl(idxa[kk], j, 64); \
            uint2 v_ = hp2[(size_t)s_ * 16 + sl]; \
            ax += h2f_lo(v_.x); ay += h2f_hi(v_.x); \
            az += h2f_lo(v_.y); aw += h2f_hi(v_.y); } \
        for (int j = 64 + g; j < (dgv); j += 4) {   /* astronomically rare */ \
            int s_ = csr[(e0v) + j]; \
            uint2 v_ = hp2[(size_t)s_ * 16 + sl]; \
            ax += h2f_lo(v_.x); ay += h2f_hi(v_.x); \
            az += h2f_lo(v_.y); aw += h2f_hi(v_.y); } } \
    ax += __shfl_xor(ax, 16, 64); ax += __shfl_xor(ax, 32, 64); \
    ay += __shfl_xor(ay, 16, 64); ay += __shfl_xor(ay, 32, 64); \
    az += __shfl_xor(az, 16, 64); az += __shfl_xor(az, 32, 64); \
    aw += __shfl_xor(aw, 16, 64); aw += __shfl_xor(aw, 32, 64); \
    if (tile * 16 + (kk) < N) { \
        ax = fmaf(eps1, h2f_lo(sf.x), ax); ay = fmaf(eps1, h2f_hi(sf.x), ay); \
        az = fmaf(eps1, h2f_lo(sf.y), az); aw = fmaf(eps1, h2f_hi(sf.y), aw); } \
    if (g == 0) { \
        float4 r4_; r4_.x = ax; r4_.y = ay; r4_.z = az; r4_.w = aw; \
        *(float4*)&myrows[(kk) * 64 + sl * 4] = r4_; } }

// Fused GIN layer, R18 structure: wave = 16-node tile (autonomous).
// 16 idx loads upfront; 8 flat batches of 2 nodes; MFMA epilogue.
// R22 delta: per-node metadata from int2 (e0,deg) -- slack CSR layout.
__global__ __launch_bounds__(256, 4) void layer_kernel(
        const ushort_t* __restrict__ hin, ushort_t* __restrict__ hout,
        const int2* __restrict__ offsets2, const int* __restrict__ csr,
        const ushort_t* __restrict__ wt_hi, const ushort_t* __restrict__ wt_lo,
        const float* __restrict__ gin_b, const float* __restrict__ eps_arr,
        int layer, int N, int csrTot) {
    __shared__ float rows[4 * 16 * 64];   // 16KB: 4 waves x 16 nodes x 64 f32
    int t = threadIdx.x;
    int wv = t >> 6, lane = t & 63;
    int tile = blockIdx.x * 4 + wv;
    if (tile * 16 >= N) return;           // waves independent
    float* myrows = rows + wv * 16 * 64;
    const uint2* hp2 = (const uint2*)hin;
    float eps1 = 1.0f + eps_arr[layer];

    int g  = lane >> 4;    // edge group 0..3
    int sl = lane & 15;    // uint2 slot (dims 4sl..4sl+3)

    // one coalesced int2 load covers all 16 (e0,deg) pairs for this tile
    int2 off2 = offsets2[min(tile * 16 + lane, N - 1)];
    int e0a[16], dga[16];
    #pragma unroll
    for (int k = 0; k < 16; ++k) {
        e0a[k] = __builtin_amdgcn_readlane(off2.x, k);
        dga[k] = __builtin_amdgcn_readlane(off2.y, k);
    }

    // all 16 idx loads issued upfront: independent, clamped (deterministic),
    // masked at the select (which the compiler may sink -- loads stay early).
    int idxa[16];
    #pragma unroll
    for (int k = 0; k < 16; ++k) {
        int v_ = csr[min(e0a[k] + lane, csrTot - 1)];
        idxa[k] = (lane < dga[k]) ? v_ : 0;
    }

    // 8 batches x 2 nodes: all 14 loads textually before any consumption.
    #pragma unroll
    for (int kb = 0; kb < 8; ++kb) {
        const int k = kb * 2;
        int e0A = e0a[k],     dgA = dga[k];
        int e0B = e0a[k + 1], dgB = dga[k + 1];
        uint2 b[6], c[6];
        #pragma unroll
        for (int j = 0; j < 6; ++j) {
            int p = g + 4 * j;
            int s = (p < dgA) ? __shfl(idxa[k], p, 64) : 0;
            b[j] = hp2[(size_t)s * 16 + sl];          // masked -> row 0 (L1)
        }
        #pragma unroll
        for (int j = 0; j < 6; ++j) {
            int p = g + 4 * j;
            int s = (p < dgB) ? __shfl(idxa[k + 1], p, 64) : 0;
            c[j] = hp2[(size_t)s * 16 + sl];
        }
        uint2 sfA = hp2[(size_t)min(tile * 16 + k,     N - 1) * 16 + sl];
        uint2 sfB = hp2[(size_t)min(tile * 16 + k + 1, N - 1) * 16 + sl];
        __builtin_amdgcn_sched_barrier(0);   // pin: loads above, consume below
        CONSUME_NODE(k,     dgA, e0A, b, sfA)
        CONSUME_NODE(k + 1, dgB, e0B, c, sfB)
    }
    // intra-wave LDS ordering: compiler emits lgkmcnt before reads; no barrier.

    int c2 = lane & 15;    // node within tile / n-index
    int q  = lane >> 4;    // quad
    int node16 = tile * 16 + c2;

    const ushort_t* Whi = wt_hi + layer * 4096;
    const ushort_t* Wlo = wt_lo + layer * 4096;
    const float*    bl  = gin_b + layer * 64;

    v8bf bhi[2], blo2[2];
    #pragma unroll
    for (int kt = 0; kt < 2; ++kt) {
        float4 f0 = *(float4*)&myrows[c2 * 64 + kt * 32 + q * 8];
        float4 f1 = *(float4*)&myrows[c2 * 64 + kt * 32 + q * 8 + 4];
        float xs[8] = {f0.x, f0.y, f0.z, f0.w, f1.x, f1.y, f1.z, f1.w};
        #pragma unroll
        for (int j = 0; j < 8; ++j) {
            __bf16 h = (__bf16)xs[j];
            bhi[kt][j] = h;
            blo2[kt][j] = (__bf16)(xs[j] - (float)h);
        }
    }

    #pragma unroll
    for (int mt = 0; mt < 4; ++mt) {
        v4f acc = {0.f, 0.f, 0.f, 0.f};
        #pragma unroll
        for (int kt = 0; kt < 2; ++kt) {
            int dim = mt * 16 + c2;
            size_t off = (size_t)dim * 64 + kt * 32 + q * 8;
            v8bf ah = __builtin_bit_cast(v8bf, *(const uint4*)(Whi + off));
            v8bf al = __builtin_bit_cast(v8bf, *(const uint4*)(Wlo + off));
            acc = __builtin_amdgcn_mfma_f32_16x16x32_bf16(ah, bhi[kt],  acc, 0, 0, 0);
            acc = __builtin_amdgcn_mfma_f32_16x16x32_bf16(ah, blo2[kt], acc, 0, 0, 0);
            acc = __builtin_amdgcn_mfma_f32_16x16x32_bf16(al, bhi[kt],  acc, 0, 0, 0);
        }
        float4 bv = ((const float4*)(bl + mt * 16))[q];
        float o0 = fmaxf(acc[0] + bv.x, 0.f);
        float o1 = fmaxf(acc[1] + bv.y, 0.f);
        float o2 = fmaxf(acc[2] + bv.z, 0.f);
        float o3 = fmaxf(acc[3] + bv.w, 0.f);
        uint2 pk;
        pk.x = f2h(o0) | (f2h(o1) << 16);
        pk.y = f2h(o2) | (f2h(o3) << 16);
        if (node16 < N)
            *(uint2*)(hout + (size_t)node16 * 64 + mt * 16 + q * 4) = pk;
    }
}

// Fused readout + MLP: block = graph, 384 threads = 6 waves (layer l = w>>1,
// node-parity p = w&1). Each wave sums 4 nodes/iter via uint2, shfl_xor
// reduce, LDS combine across parities, then the 2-layer MLP.
__global__ __launch_bounds__(384) void readout_mlp_kernel(
        const ushort_t* __restrict__ H, const int* __restrict__ gids,
        const float* __restrict__ W1, const float* __restrict__ b1,
        const float* __restrict__ W2, const float* __restrict__ b2,
        float* __restrict__ out, int N) {
    __shared__ float part[6][64];
    __shared__ float gr[192];
    __shared__ float hid[128];
    int graph = blockIdx.x;
    int t = threadIdx.x;
    int w = t >> 6, lane = t & 63;
    int l = w >> 1, p = w & 1;
    int lo = 0, hi = N;
    while (lo < hi) { int m = (lo + hi) >> 1; if (gids[m] < graph) lo = m + 1; else hi = m; }
    int start = lo;
    int lo2 = start, hi2 = N;
    while (lo2 < hi2) { int m = (lo2 + hi2) >> 1; if (gids[m] < graph + 1) lo2 = m + 1; else hi2 = m; }
    int end = lo2;
    int nd  = lane >> 4;            // node-phase 0..3
    int slp = lane & 15;            // uint2 slot (dims 4slp..4slp+3)
    float a0 = 0.f, a1 = 0.f, a2 = 0.f, a3 = 0.f;
    const uint2* Hl = (const uint2*)(H + (size_t)l * N * 64);
    for (int n = start + p * 4 + nd; n < end; n += 8) {
        uint2 v = Hl[(size_t)n * 16 + slp];
        a0 += h2f_lo(v.x); a1 += h2f_hi(v.x);
        a2 += h2f_lo(v.y); a3 += h2f_hi(v.y);
    }
    a0 += __shfl_xor(a0, 16, 64); a0 += __shfl_xor(a0, 32, 64);
    a1 += __shfl_xor(a1, 16, 64); a1 += __shfl_xor(a1, 32, 64);
    a2 += __shfl_xor(a2, 16, 64); a2 += __shfl_xor(a2, 32, 64);
    a3 += __shfl_xor(a3, 16, 64); a3 += __shfl_xor(a3, 32, 64);
    if (lane < 16) {
        float4 r4; r4.x = a0; r4.y = a1; r4.z = a2; r4.w = a3;
        *(float4*)&part[w][slp * 4] = r4;
    }
    __syncthreads();
    if (t < 192) {
        int ll = t >> 6, d = t & 63;
        gr[t] = part[ll * 2][d] + part[ll * 2 + 1][d];
    }
    __syncthreads();
    if (t < 128) {
        float s = b1[t];
        for (int k = 0; k < 192; ++k) s = fmaf(gr[k], W1[k * 128 + t], s);
        hid[t] = fmaxf(s, 0.0f);
    }
    __syncthreads();
    if (t < 32) {
        float s = b2[t];
        for (int k = 0; k < 128; ++k) s = fmaf(hid[k], W2[k * 32 + t], s);
        out[graph * 32 + t] = s;
    }
}

extern "C" void kernel_launch(void* const* d_in, const int* in_sizes, int n_in,
                              void* d_out, int out_size, void* d_ws, size_t ws_size,
                              hipStream_t stream) {
    const float* x     = (const float*)d_in[0];
    const float* gin_W = (const float*)d_in[1];
    const float* gin_b = (const float*)d_in[2];
    const float* eps   = (const float*)d_in[3];
    const float* r_W1  = (const float*)d_in[4];
    const float* r_b1  = (const float*)d_in[5];
    const float* r_W2  = (const float*)d_in[6];
    const float* r_b2  = (const float*)d_in[7];
    const int*   src   = (const int*)d_in[8];
    const int*   dst   = (const int*)d_in[9];
    const int*   gids  = (const int*)d_in[10];

    int N = in_sizes[0] / 64;       // 100000
    int E = in_sizes[8];            // 1200000
    int B = out_size / 32;          // 256

    int nbkt = (N + BS - 1) / BS;   // 196 (<= 256)
    int ebpb = (E + NBLK - 1) / NBLK;
    int n4 = N * 64 / 4;
    int castBlocks = (n4 + 255) / 256;
    int wtotal = 3 * 4096;
    int prepBlocks = (wtotal + 255) / 256;
    int csrTot = nbkt << CAPSH;     // slack csr/bkt size (196*8192)

    // workspace layout (4B words), all regions fully written before read:
    //   cnt[nbkt] | offsets2[N int2] | bkt[nbkt<<13] | csr[nbkt<<13] | pad
    //   xh[N*64 f16] | H[3*N*64 f16] | whi[3*4096] | wlo[3*4096]
    int* ws       = (int*)d_ws;
    int* cnt      = ws;
    int2* offsets2 = (int2*)(cnt + nbkt);
    unsigned int* bkt = (unsigned int*)(offsets2 + N);
    int* csr      = (int*)(bkt + csrTot);
    size_t w      = (size_t)(csr + csrTot - ws);
    w = (w + 15) & ~(size_t)15;     // 64B align
    ushort_t* xh  = (ushort_t*)(ws + w);
    ushort_t* H   = xh + (size_t)N * 64;
    ushort_t* whi = H + 3 * (size_t)N * 64;
    ushort_t* wlo = whi + 3 * 4096;

    hipMemsetAsync(cnt, 0, nbkt * sizeof(int), stream);    // capturable memset
    scatter_pre_kernel<<<NBLK + castBlocks + prepBlocks, 256, 0, stream>>>(
        src, dst, cnt, bkt, E, nbkt, ebpb,
        x, xh, n4, castBlocks, gin_W, whi, wlo, wtotal);
    csr_build_kernel<<<nbkt, 256, 0, stream>>>(bkt, cnt, offsets2, csr, N);

    int lbk = (N + 63) / 64;        // 4 tiles (waves) of 16 nodes per block
    ushort_t* H0 = H;
    ushort_t* H1 = H + (size_t)N * 64;
    ushort_t* H2 = H + 2 * (size_t)N * 64;

    layer_kernel<<<lbk, 256, 0, stream>>>(xh, H0, offsets2, csr, whi, wlo, gin_b, eps, 0, N, csrTot);
    layer_kernel<<<lbk, 256, 0, stream>>>(H0, H1, offsets2, csr, whi, wlo, gin_b, eps, 1, N, csrTot);
    layer_kernel<<<lbk, 256, 0, stream>>>(H1, H2, offsets2, csr, whi, wlo, gin_b, eps, 2, N, csrTot);

    readout_mlp_kernel<<<B, 384, 0, stream>>>(H, gids, r_W1, r_b1, r_W2, r_b2, (float*)d_out, N);
}